// Round 1
// baseline (1604.765 us; speedup 1.0000x reference)
//
#include <hip/hip_runtime.h>
#include <cstdint>

#define B_SZ 2048
#define SEQ  16
#define DIM  1024
#define HID  512
#define DK   512
#define NH   4
#define DH   128
#define GATE 2048
#define EPSV 1e-5f

typedef __bf16 bf8_t __attribute__((ext_vector_type(8)));
typedef float  f4_t  __attribute__((ext_vector_type(4)));
typedef unsigned short u16x8 __attribute__((ext_vector_type(8)));
typedef unsigned short u16x4 __attribute__((ext_vector_type(4)));

__device__ __forceinline__ unsigned short f2bf(float f){
  __bf16 h = (__bf16)f;                       // RNE
  return __builtin_bit_cast(unsigned short, h);
}
__device__ __forceinline__ float bf2f(unsigned short u){
  return __builtin_bit_cast(float, ((unsigned int)u) << 16);
}
__device__ __forceinline__ float sigm(float x){ return 1.f/(1.f+__expf(-x)); }
__device__ __forceinline__ float tanh_f(float x){ return 1.f - 2.f/(__expf(2.f*x)+1.f); }

// ---------------- generic BT GEMM: C(MxN) = A(MxK) @ B(NxK)^T [+bias][relu] ----------------
// A source split into up to 4 column-blocks of width kPerSrc (kPerSrc == per-source row stride).
template<bool A_F32, bool OUT_BF16, bool BIAS, bool RELU>
__global__ __launch_bounds__(256) void gemm_bt(
    const void* __restrict__ A0, const void* __restrict__ A1,
    const void* __restrict__ A2, const void* __restrict__ A3,
    const unsigned short* __restrict__ Bw,
    const float* __restrict__ bias,
    void* __restrict__ Cp,
    int N, int K, int kPerSrc)
{
  constexpr int BM=128, BN=128, BK=64;
  __shared__ __align__(16) unsigned short As[BM][BK+8];
  __shared__ __align__(16) unsigned short Bs[BN][BK+8];
  const int tid  = threadIdx.x;
  const int bm0  = blockIdx.y*BM, bn0 = blockIdx.x*BN;
  const int lane = tid & 63, wave = tid >> 6;
  const int wm = (wave&1)*64, wn = (wave>>1)*64;
  const int fr = lane & 15, kg = lane >> 4;

  f4_t acc[4][4];
  #pragma unroll
  for (int m=0;m<4;++m)
    #pragma unroll
    for (int n=0;n<4;++n) acc[m][n] = (f4_t)0.f;

  f4_t  ra0[4], ra1[4];   // fp32 A staging
  u16x8 raB[4];           // bf16 A staging
  u16x8 rb[4];            // B staging

  auto loadA = [&](int kt){
    int ks = kt*BK;
    int si = ks / kPerSrc;
    int kc = ks - si*kPerSrc;
    const void* Asel = si==0?A0 : si==1?A1 : si==2?A2 : A3;
    #pragma unroll
    for (int q=0;q<4;++q){
      int r = q*32 + (tid>>3);
      size_t off = (size_t)(bm0+r)*kPerSrc + kc + (tid&7)*8;
      if constexpr (A_F32){
        const f4_t* ap = (const f4_t*)((const float*)Asel + off);
        ra0[q] = ap[0]; ra1[q] = ap[1];
      } else {
        raB[q] = *(const u16x8*)((const unsigned short*)Asel + off);
      }
    }
  };
  auto loadB = [&](int kt){
    #pragma unroll
    for (int q=0;q<4;++q){
      int r = q*32 + (tid>>3);
      rb[q] = *(const u16x8*)(Bw + (size_t)(bn0+r)*K + kt*BK + (tid&7)*8);
    }
  };
  auto storeLDS = [&](){
    #pragma unroll
    for (int q=0;q<4;++q){
      int r = q*32 + (tid>>3), c = (tid&7)*8;
      u16x8 w;
      if constexpr (A_F32){
        #pragma unroll
        for (int j=0;j<4;++j){ w[j] = f2bf(ra0[q][j]); w[4+j] = f2bf(ra1[q][j]); }
      } else w = raB[q];
      *(u16x8*)&As[r][c] = w;
      *(u16x8*)&Bs[r][c] = rb[q];
    }
  };

  const int KT = K/BK;
  loadA(0); loadB(0);
  for (int kt=0; kt<KT; ++kt){
    __syncthreads();
    storeLDS();
    __syncthreads();
    if (kt+1 < KT){ loadA(kt+1); loadB(kt+1); }
    #pragma unroll
    for (int kk=0;kk<2;++kk){
      bf8_t af[4], bfr[4];
      #pragma unroll
      for (int m=0;m<4;++m) af[m]  = *(const bf8_t*)&As[wm+m*16+fr][kk*32+kg*8];
      #pragma unroll
      for (int n=0;n<4;++n) bfr[n] = *(const bf8_t*)&Bs[wn+n*16+fr][kk*32+kg*8];
      #pragma unroll
      for (int m=0;m<4;++m)
        #pragma unroll
        for (int n=0;n<4;++n)
          acc[m][n] = __builtin_amdgcn_mfma_f32_16x16x32_bf16(af[m], bfr[n], acc[m][n], 0,0,0);
    }
  }
  #pragma unroll
  for (int n=0;n<4;++n){
    int col = bn0 + wn + n*16 + fr;
    float bv = 0.f;
    if constexpr (BIAS) bv = bias[col];
    #pragma unroll
    for (int m=0;m<4;++m){
      #pragma unroll
      for (int j=0;j<4;++j){
        int row = bm0 + wm + m*16 + kg*4 + j;
        float v = acc[m][n][j] + bv;
        if constexpr (RELU) v = fmaxf(v, 0.f);
        if constexpr (OUT_BF16) ((unsigned short*)Cp)[(size_t)row*N + col] = f2bf(v);
        else                    ((float*)Cp)[(size_t)row*N + col] = v;
      }
    }
  }
}

// ---------------- fused LN + LSTM elementwise step (one WG per batch row) ----------------
__global__ __launch_bounds__(256) void lstm_step(
  const float* __restrict__ X, const float* __restrict__ Gh,
  const float* __restrict__ c_src, float* __restrict__ c_dst,
  const float* __restrict__ g_ih, const float* __restrict__ b_ih,
  const float* __restrict__ g_hh, const float* __restrict__ b_hh,
  const float* __restrict__ g_c,  const float* __restrict__ b_c,
  unsigned short* __restrict__ h_out, unsigned short* __restrict__ lstm_out,
  int t)
{
  const int b = blockIdx.x, tid = threadIdx.x;
  __shared__ float xs[GATE];
  __shared__ float gs[GATE];
  __shared__ float red[32];
  const float* xrow = X  + ((size_t)b*SEQ + t)*GATE;
  const float* grow = Gh + (size_t)b*GATE;
  f4_t x0 = *(const f4_t*)&xrow[tid*8];
  f4_t x1 = *(const f4_t*)&xrow[tid*8+4];
  f4_t g0 = *(const f4_t*)&grow[tid*8];
  f4_t g1 = *(const f4_t*)&grow[tid*8+4];
  *(f4_t*)&xs[tid*8]   = x0; *(f4_t*)&xs[tid*8+4] = x1;
  *(f4_t*)&gs[tid*8]   = g0; *(f4_t*)&gs[tid*8+4] = g1;
  float sx=0,sx2=0,sg=0,sg2=0;
  #pragma unroll
  for (int j=0;j<4;++j){
    sx += x0[j]+x1[j]; sx2 += x0[j]*x0[j]+x1[j]*x1[j];
    sg += g0[j]+g1[j]; sg2 += g0[j]*g0[j]+g1[j]*g1[j];
  }
  #pragma unroll
  for (int m=32;m;m>>=1){
    sx += __shfl_xor(sx,m); sx2 += __shfl_xor(sx2,m);
    sg += __shfl_xor(sg,m); sg2 += __shfl_xor(sg2,m);
  }
  const int w = tid>>6;
  if ((tid&63)==0){ red[w]=sx; red[4+w]=sx2; red[8+w]=sg; red[12+w]=sg2; }
  __syncthreads();
  sx  = red[0]+red[1]+red[2]+red[3];
  sx2 = red[4]+red[5]+red[6]+red[7];
  sg  = red[8]+red[9]+red[10]+red[11];
  sg2 = red[12]+red[13]+red[14]+red[15];
  const float mX = sx*(1.f/GATE), mH = sg*(1.f/GATE);
  const float rX = rsqrtf(sx2*(1.f/GATE)-mX*mX+EPSV);
  const float rH = rsqrtf(sg2*(1.f/GATE)-mH*mH+EPSV);

  float cN[2], xo[2]; float sc=0, sc2=0;
  #pragma unroll
  for (int rep=0;rep<2;++rep){
    const int n = tid + rep*256;
    const int ni=n, nf=n+HID, ng=n+2*HID, no=n+3*HID;
    float gi = (xs[ni]-mX)*rX*g_ih[ni]+b_ih[ni] + (gs[ni]-mH)*rH*g_hh[ni]+b_hh[ni];
    float gf = (xs[nf]-mX)*rX*g_ih[nf]+b_ih[nf] + (gs[nf]-mH)*rH*g_hh[nf]+b_hh[nf];
    float gg = (xs[ng]-mX)*rX*g_ih[ng]+b_ih[ng] + (gs[ng]-mH)*rH*g_hh[ng]+b_hh[ng];
    float go = (xs[no]-mX)*rX*g_ih[no]+b_ih[no] + (gs[no]-mH)*rH*g_hh[no]+b_hh[no];
    float co = c_src[(size_t)b*HID + n];
    float cn = sigm(gf)*co + sigm(gi)*tanh_f(gg);
    cN[rep]=cn; xo[rep]=go;
    sc += cn; sc2 += cn*cn;
  }
  #pragma unroll
  for (int m=32;m;m>>=1){ sc += __shfl_xor(sc,m); sc2 += __shfl_xor(sc2,m); }
  if ((tid&63)==0){ red[16+w]=sc; red[20+w]=sc2; }
  __syncthreads();
  sc  = red[16]+red[17]+red[18]+red[19];
  sc2 = red[20]+red[21]+red[22]+red[23];
  const float mC = sc*(1.f/HID);
  const float rC = rsqrtf(sc2*(1.f/HID)-mC*mC+EPSV);
  #pragma unroll
  for (int rep=0;rep<2;++rep){
    const int n = tid + rep*256;
    float hN = sigm(xo[rep])*tanh_f((cN[rep]-mC)*rC*g_c[n]+b_c[n]);
    c_dst[(size_t)b*HID+n] = cN[rep];
    unsigned short hbv = f2bf(hN);
    h_out[(size_t)b*HID+n] = hbv;
    lstm_out[((size_t)b*SEQ+t)*HID+n] = hbv;
  }
}

// ---------------- fused attention: scores -> softmax -> pooled -> scalar out ----------------
__global__ __launch_bounds__(256) void attn_out_k(
  const float* __restrict__ q, const unsigned short* __restrict__ Km,
  const unsigned short* __restrict__ lo_all,
  const float* __restrict__ u, const float* __restrict__ Cc,
  float* __restrict__ out)
{
  const int b = blockIdx.x, tid = threadIdx.x;
  __shared__ float qs[DK];
  __shared__ float sc[NH][SEQ];
  __shared__ float at[NH][SEQ];
  __shared__ float red[4];
  for (int i=tid; i<DK; i+=256) qs[i] = q[(size_t)b*DK + i];
  __syncthreads();
  {
    const int p = tid>>2, sub = tid&3, h = p>>4, s = p&15;
    const unsigned short* krow = Km + ((size_t)b*SEQ + s)*DK + h*DH + sub*32;
    const float* qh = &qs[h*DH + sub*32];
    float part = 0.f;
    #pragma unroll
    for (int c8=0;c8<4;++c8){
      u16x8 kv = *(const u16x8*)(krow + c8*8);
      #pragma unroll
      for (int j=0;j<8;++j) part += qh[c8*8+j]*bf2f(kv[j]);
    }
    part += __shfl_xor(part,1); part += __shfl_xor(part,2);
    if (sub==0) sc[h][s] = part * 0.08838834764831845f;  // 1/sqrt(128)
  }
  __syncthreads();
  if (tid < 64){
    const int h = tid>>4;
    float v = sc[h][tid&15], mx = v;
    #pragma unroll
    for (int m=1;m<16;m<<=1) mx = fmaxf(mx, __shfl_xor(mx,m));
    float e = __expf(v-mx), se = e;
    #pragma unroll
    for (int m=1;m<16;m<<=1) se += __shfl_xor(se,m);
    at[h][tid&15] = e/se;
  }
  __syncthreads();
  float accum = 0.f;
  #pragma unroll
  for (int it=0; it<4; ++it){
    const int idx = it*256 + tid;
    const int h = idx>>8, d0 = (idx&255)*2;
    const unsigned short* lo = lo_all + (size_t)b*SEQ*HID + d0;
    float p0=0.f, p1=0.f;
    #pragma unroll
    for (int s=0;s<16;++s){
      unsigned int pr = *(const unsigned int*)(lo + s*HID);
      float a = at[h][s];
      p0 += a*bf2f((unsigned short)(pr&0xffffu));
      p1 += a*bf2f((unsigned short)(pr>>16));
    }
    accum += u[h*HID+d0]*p0 + u[h*HID+d0+1]*p1;
  }
  #pragma unroll
  for (int m=32;m;m>>=1) accum += __shfl_xor(accum,m);
  if ((tid&63)==0) red[tid>>6] = accum;
  __syncthreads();
  if (tid==0) out[1+b] = red[0]+red[1]+red[2]+red[3] + Cc[0];
}

__global__ __launch_bounds__(256) void loss_k(const float* __restrict__ label, float* __restrict__ out){
  const int tid = threadIdx.x;
  __shared__ float red[4];
  float s = 0.f;
  for (int b=tid; b<B_SZ; b+=256){
    float d = out[1+b] - label[(size_t)b*SEQ + (SEQ-1)];
    s += d*d;
  }
  #pragma unroll
  for (int m=32;m;m>>=1) s += __shfl_xor(s,m);
  if ((tid&63)==0) red[tid>>6]=s;
  __syncthreads();
  if (tid==0) out[0] = (red[0]+red[1]+red[2]+red[3]) * (1.f/B_SZ);
}

__global__ __launch_bounds__(256) void cvt_bf16_k(const float* __restrict__ in, unsigned short* __restrict__ o, int n){
  int i = (blockIdx.x*256 + threadIdx.x)*4;
  if (i < n){
    f4_t v = *(const f4_t*)&in[i];
    u16x4 w;
    #pragma unroll
    for (int j=0;j<4;++j) w[j] = f2bf(v[j]);
    *(u16x4*)&o[i] = w;
  }
}

// Fold wout/out_W/wv into u[h,d] and scalar C (exact algebra: sum(attn)==1).
__global__ __launch_bounds__(256) void fold_out_k(
  const float* __restrict__ wout_W, const float* __restrict__ wout_b,
  const float* __restrict__ out_W,  const float* __restrict__ out_b,
  const float* __restrict__ wv_W,   const float* __restrict__ wv_b,
  float* __restrict__ u, float* __restrict__ Cc)
{
  __shared__ float we[2048];
  __shared__ float red[4];
  const int tid = threadIdx.x;
  for (int j=tid; j<2048; j+=256){
    float s=0.f;
    for (int m=0;m<512;++m) s += out_W[m]*wout_W[(size_t)m*2048+j];
    we[j]=s;
  }
  __syncthreads();
  for (int o=tid; o<2048; o+=256){
    const int h=o>>9, d=o&511;
    float s=0.f;
    const float* wv = wv_W + (size_t)h*512*512 + d;
    const float* wp = &we[h*512];
    for (int k2=0;k2<512;++k2) s += wp[k2]*wv[(size_t)k2*512];
    u[o]=s;
  }
  float cp=0.f;
  for (int j=tid;j<2048;j+=256) cp += we[j]*wv_b[j];
  for (int m=tid;m<512;m+=256)  cp += out_W[m]*wout_b[m];
  #pragma unroll
  for (int m=32;m;m>>=1) cp += __shfl_xor(cp,m);
  if ((tid&63)==0) red[tid>>6]=cp;
  __syncthreads();
  if (tid==0) Cc[0] = red[0]+red[1]+red[2]+red[3] + out_b[0];
}

extern "C" void kernel_launch(void* const* d_in, const int* in_sizes, int n_in,
                              void* d_out, int out_size, void* d_ws, size_t ws_size,
                              hipStream_t stream)
{
  const float* visual = (const float*)d_in[0];
  const float* text   = (const float*)d_in[1];
  const float* user_  = (const float*)d_in[2];
  const float* cat_   = (const float*)d_in[3];
  const float* label  = (const float*)d_in[4];
  const float* h0     = (const float*)d_in[5];
  const float* c0     = (const float*)d_in[6];
  const float* fus_W  = (const float*)d_in[7];
  const float* fus_b  = (const float*)d_in[8];
  const float* W_ih   = (const float*)d_in[9];
  const float* W_hh   = (const float*)d_in[10];
  const float* g_ih   = (const float*)d_in[11];
  const float* b_ih   = (const float*)d_in[12];
  const float* g_hh   = (const float*)d_in[13];
  const float* b_hh   = (const float*)d_in[14];
  const float* g_c    = (const float*)d_in[15];
  const float* b_c    = (const float*)d_in[16];
  const float* wq_W   = (const float*)d_in[17];
  const float* wq_b   = (const float*)d_in[18];
  const float* wk_W   = (const float*)d_in[19];
  const float* wk_b   = (const float*)d_in[20];
  const float* wv_W   = (const float*)d_in[21];
  const float* wv_b   = (const float*)d_in[22];
  const float* wout_W = (const float*)d_in[23];
  const float* wout_b = (const float*)d_in[24];
  const float* out_W  = (const float*)d_in[25];
  const float* out_b  = (const float*)d_in[26];
  (void)in_sizes; (void)n_in; (void)out_size; (void)ws_size;

  char* base = (char*)d_ws; size_t off = 0;
  auto alloc = [&](size_t n)->void*{ void* p = base+off; off += n; off = (off+255)&~(size_t)255; return p; };
  unsigned short* vt   = (unsigned short*)alloc((size_t)32768*1024*2);
  float*          X    = (float*)         alloc((size_t)32768*2048*4);
  float*          Gh   = (float*)         alloc((size_t)2048*2048*4);
  float*          cws  = (float*)         alloc((size_t)2048*512*4);
  unsigned short* hb   = (unsigned short*)alloc((size_t)2048*512*2);
  unsigned short* lo   = (unsigned short*)alloc((size_t)32768*512*2);
  unsigned short* Km   = (unsigned short*)alloc((size_t)32768*512*2);
  float*          qb   = (float*)         alloc((size_t)2048*512*4);
  unsigned short* fusWb= (unsigned short*)alloc((size_t)1024*4096*2);
  unsigned short* Wihb = (unsigned short*)alloc((size_t)2048*1024*2);
  unsigned short* Whhb = (unsigned short*)alloc((size_t)2048*512*2);
  unsigned short* wqb  = (unsigned short*)alloc((size_t)512*512*2);
  unsigned short* wkb  = (unsigned short*)alloc((size_t)512*512*2);
  float*          u_ws = (float*)         alloc(2048*4);
  float*          C_ws = (float*)         alloc(256);

  // weight / h0 conversion to bf16
  cvt_bf16_k<<<dim3(4096), dim3(256), 0, stream>>>(fus_W, fusWb, 1024*4096);
  cvt_bf16_k<<<dim3(2048), dim3(256), 0, stream>>>(W_ih,  Wihb,  2048*1024);
  cvt_bf16_k<<<dim3(1024), dim3(256), 0, stream>>>(W_hh,  Whhb,  2048*512);
  cvt_bf16_k<<<dim3(256),  dim3(256), 0, stream>>>(wq_W,  wqb,   512*512);
  cvt_bf16_k<<<dim3(256),  dim3(256), 0, stream>>>(wk_W,  wkb,   512*512);
  cvt_bf16_k<<<dim3(1024), dim3(256), 0, stream>>>(h0,    hb,    2048*512);
  fold_out_k<<<dim3(1), dim3(256), 0, stream>>>(wout_W, wout_b, out_W, out_b, wv_W, wv_b, u_ws, C_ws);

  // GEMM1: v_t = relu(mods @ fus_W^T + fus_b)   M=32768 N=1024 K=4096 (4 sources of 1024)
  gemm_bt<true,true,true,true><<<dim3(8,256), dim3(256), 0, stream>>>(
      visual, text, user_, cat_, fusWb, fus_b, vt, 1024, 4096, 1024);
  // GEMM2: X = v_t @ W_ih^T    M=32768 N=2048 K=1024  (fp32 out, LN done per-step)
  gemm_bt<false,false,false,false><<<dim3(16,256), dim3(256), 0, stream>>>(
      vt, vt, vt, vt, Wihb, nullptr, X, 2048, 1024, 1024);

  // recurrence
  for (int t=0; t<SEQ; ++t){
    gemm_bt<false,false,false,false><<<dim3(16,16), dim3(256), 0, stream>>>(
        hb, hb, hb, hb, Whhb, nullptr, Gh, 2048, 512, 512);
    lstm_step<<<dim3(2048), dim3(256), 0, stream>>>(
        X, Gh, (t==0 ? c0 : cws), cws, g_ih, b_ih, g_hh, b_hh, g_c, b_c, hb, lo, t);
  }

  // q = hn @ wq_W^T + wq_b   (fp32 out)
  gemm_bt<false,false,true,false><<<dim3(4,16), dim3(256), 0, stream>>>(
      hb, hb, hb, hb, wqb, wq_b, qb, 512, 512, 512);
  // Kmat = lstm_out @ wk_W^T + wk_b  (bf16 out)
  gemm_bt<false,true,true,false><<<dim3(4,256), dim3(256), 0, stream>>>(
      lo, lo, lo, lo, wkb, wk_b, Km, 512, 512, 512);

  attn_out_k<<<dim3(2048), dim3(256), 0, stream>>>(qb, Km, lo, u_ws, C_ws, (float*)d_out);
  loss_k<<<dim3(1), dim3(256), 0, stream>>>(label, (float*)d_out);
}

// Round 2
// 1187.220 us; speedup vs baseline: 1.3517x; 1.3517x over previous
//
#include <hip/hip_runtime.h>
#include <cstdint>

#define B_SZ 2048
#define SEQ  16
#define DIM  1024
#define HID  512
#define DK   512
#define NH   4
#define DH   128
#define GATE 2048
#define EPSV 1e-5f

typedef __bf16 bf8_t __attribute__((ext_vector_type(8)));
typedef float  f4_t  __attribute__((ext_vector_type(4)));
typedef unsigned short u16x8 __attribute__((ext_vector_type(8)));
typedef unsigned short u16x4 __attribute__((ext_vector_type(4)));

__device__ __forceinline__ unsigned short f2bf(float f){
  __bf16 h = (__bf16)f;                       // RNE
  return __builtin_bit_cast(unsigned short, h);
}
__device__ __forceinline__ float bf2f(unsigned short u){
  return __builtin_bit_cast(float, ((unsigned int)u) << 16);
}
__device__ __forceinline__ float sigm(float x){ return 1.f/(1.f+__expf(-x)); }
__device__ __forceinline__ float tanh_f(float x){ return 1.f - 2.f/(__expf(2.f*x)+1.f); }

__device__ __forceinline__ void gload16(const void* g, void* l){
  __builtin_amdgcn_global_load_lds(
      (const __attribute__((address_space(1))) void*)g,
      (__attribute__((address_space(3))) void*)l, 16, 0, 0);
}

// ------------- unified bf16 BT GEMM (m97 structure): C = A(MxK) @ B(NxK)^T -------------
// global_load_lds 16B staging, linear LDS, 2-barrier K-loop, chunked XCD swizzle.
template<bool OUT_BF16, bool BIAS, bool RELU>
__global__ __launch_bounds__(256) void gemm16(
    const unsigned short* __restrict__ A,
    const unsigned short* __restrict__ Bw,
    const float* __restrict__ bias,
    void* __restrict__ Cp,
    int N, int K, int nwg)
{
  __shared__ __align__(16) unsigned short As[128*64];
  __shared__ __align__(16) unsigned short Bs[128*64];
  const int tid = threadIdx.x, lane = tid & 63, wave = tid >> 6;
  const int bid = blockIdx.x;
  // bijective chunked XCD swizzle (nwg % 8 == 0 for every call site)
  const int swz = (bid & 7)*(nwg >> 3) + (bid >> 3);
  const int nx  = N >> 7;
  const int lnx = 31 - __clz(nx);
  const int bm0 = (swz >> lnx) << 7;
  const int bn0 = (swz & (nx-1)) << 7;

  // staging addresses: chunk c = wave*4+q covers rows [c*8, c*8+8); lane l -> row c*8+l/8, col (l&7)*8
  const unsigned short* Ab = A  + (size_t)(bm0 + wave*32 + (lane>>3))*K + (lane&7)*8;
  const unsigned short* Bb = Bw + (size_t)(bn0 + wave*32 + (lane>>3))*K + (lane&7)*8;
  unsigned short* la = As + wave*2048;   // wave-uniform LDS base
  unsigned short* lb = Bs + wave*2048;

  f4_t acc[4][4];
  #pragma unroll
  for (int m=0;m<4;++m)
    #pragma unroll
    for (int n=0;n<4;++n) acc[m][n] = (f4_t)0.f;

  const int KT = K >> 6;
  const int fr = lane & 15, kg = lane >> 4;
  const int wm = (wave & 1)*64, wn = (wave >> 1)*64;

  for (int kt = 0; kt < KT; ++kt){
    if (kt) __syncthreads();                       // all waves done reading LDS
    const size_t ko = (size_t)kt*64;
    #pragma unroll
    for (int q = 0; q < 4; ++q){
      gload16(Ab + ko + (size_t)q*8*K, la + q*512);
      gload16(Bb + ko + (size_t)q*8*K, lb + q*512);
    }
    __syncthreads();                               // vmcnt(0) drained -> tiles ready
    #pragma unroll
    for (int kk = 0; kk < 2; ++kk){
      bf8_t af[4], bf_[4];
      #pragma unroll
      for (int m=0;m<4;++m) af[m]  = *(const bf8_t*)&As[(wm+m*16+fr)*64 + kk*32 + kg*8];
      #pragma unroll
      for (int n=0;n<4;++n) bf_[n] = *(const bf8_t*)&Bs[(wn+n*16+fr)*64 + kk*32 + kg*8];
      #pragma unroll
      for (int m=0;m<4;++m)
        #pragma unroll
        for (int n=0;n<4;++n)
          acc[m][n] = __builtin_amdgcn_mfma_f32_16x16x32_bf16(af[m], bf_[n], acc[m][n], 0,0,0);
    }
  }

  #pragma unroll
  for (int n=0;n<4;++n){
    const int col = bn0 + wn + n*16 + fr;
    float bv = 0.f;
    if constexpr (BIAS) bv = bias[col];
    #pragma unroll
    for (int m=0;m<4;++m){
      #pragma unroll
      for (int j=0;j<4;++j){
        const int row = bm0 + wm + m*16 + kg*4 + j;
        float v = acc[m][n][j] + bv;
        if constexpr (RELU) v = fmaxf(v, 0.f);
        if constexpr (OUT_BF16) ((unsigned short*)Cp)[(size_t)row*N + col] = f2bf(v);
        else                    ((float*)Cp)[(size_t)row*N + col] = v;
      }
    }
  }
}

// ---------------- fused LN + LSTM elementwise step (one WG per batch row) ----------------
__global__ __launch_bounds__(256) void lstm_step(
  const unsigned short* __restrict__ X, const unsigned short* __restrict__ Gh,
  const float* __restrict__ c_src, float* __restrict__ c_dst,
  const float* __restrict__ g_ih, const float* __restrict__ b_ih,
  const float* __restrict__ g_hh, const float* __restrict__ b_hh,
  const float* __restrict__ g_c,  const float* __restrict__ b_c,
  unsigned short* __restrict__ h_out, unsigned short* __restrict__ lstm_out,
  int t)
{
  const int b = blockIdx.x, tid = threadIdx.x;
  __shared__ float xs[GATE];
  __shared__ float gs[GATE];
  __shared__ float red[32];
  const unsigned short* xrow = X  + ((size_t)b*SEQ + t)*GATE;
  const unsigned short* grow = Gh + (size_t)b*GATE;
  u16x8 xv = *(const u16x8*)&xrow[tid*8];
  u16x8 gv = *(const u16x8*)&grow[tid*8];
  float sx=0,sx2=0,sg=0,sg2=0;
  #pragma unroll
  for (int j=0;j<8;++j){
    float x = bf2f(xv[j]), g = bf2f(gv[j]);
    xs[tid*8+j]=x; gs[tid*8+j]=g;
    sx += x; sx2 += x*x; sg += g; sg2 += g*g;
  }
  #pragma unroll
  for (int m=32;m;m>>=1){
    sx += __shfl_xor(sx,m); sx2 += __shfl_xor(sx2,m);
    sg += __shfl_xor(sg,m); sg2 += __shfl_xor(sg2,m);
  }
  const int w = tid>>6;
  if ((tid&63)==0){ red[w]=sx; red[4+w]=sx2; red[8+w]=sg; red[12+w]=sg2; }
  __syncthreads();
  sx  = red[0]+red[1]+red[2]+red[3];
  sx2 = red[4]+red[5]+red[6]+red[7];
  sg  = red[8]+red[9]+red[10]+red[11];
  sg2 = red[12]+red[13]+red[14]+red[15];
  const float mX = sx*(1.f/GATE), mH = sg*(1.f/GATE);
  const float rX = rsqrtf(sx2*(1.f/GATE)-mX*mX+EPSV);
  const float rH = rsqrtf(sg2*(1.f/GATE)-mH*mH+EPSV);

  float cN[2], xo[2]; float sc=0, sc2=0;
  #pragma unroll
  for (int rep=0;rep<2;++rep){
    const int n = tid + rep*256;
    const int ni=n, nf=n+HID, ng=n+2*HID, no=n+3*HID;
    float gi = (xs[ni]-mX)*rX*g_ih[ni]+b_ih[ni] + (gs[ni]-mH)*rH*g_hh[ni]+b_hh[ni];
    float gf = (xs[nf]-mX)*rX*g_ih[nf]+b_ih[nf] + (gs[nf]-mH)*rH*g_hh[nf]+b_hh[nf];
    float gg = (xs[ng]-mX)*rX*g_ih[ng]+b_ih[ng] + (gs[ng]-mH)*rH*g_hh[ng]+b_hh[ng];
    float go = (xs[no]-mX)*rX*g_ih[no]+b_ih[no] + (gs[no]-mH)*rH*g_hh[no]+b_hh[no];
    float co = c_src[(size_t)b*HID + n];
    float cn = sigm(gf)*co + sigm(gi)*tanh_f(gg);
    cN[rep]=cn; xo[rep]=go;
    sc += cn; sc2 += cn*cn;
  }
  #pragma unroll
  for (int m=32;m;m>>=1){ sc += __shfl_xor(sc,m); sc2 += __shfl_xor(sc2,m); }
  if ((tid&63)==0){ red[16+w]=sc; red[20+w]=sc2; }
  __syncthreads();
  sc  = red[16]+red[17]+red[18]+red[19];
  sc2 = red[20]+red[21]+red[22]+red[23];
  const float mC = sc*(1.f/HID);
  const float rC = rsqrtf(sc2*(1.f/HID)-mC*mC+EPSV);
  #pragma unroll
  for (int rep=0;rep<2;++rep){
    const int n = tid + rep*256;
    float hN = sigm(xo[rep])*tanh_f((cN[rep]-mC)*rC*g_c[n]+b_c[n]);
    c_dst[(size_t)b*HID+n] = cN[rep];
    unsigned short hbv = f2bf(hN);
    h_out[(size_t)b*HID+n] = hbv;
    lstm_out[((size_t)b*SEQ+t)*HID+n] = hbv;
  }
}

// ---------------- fused attention: scores -> softmax -> pooled -> scalar out ----------------
__global__ __launch_bounds__(256) void attn_out_k(
  const float* __restrict__ q, const unsigned short* __restrict__ Km,
  const unsigned short* __restrict__ lo_all,
  const float* __restrict__ u, const float* __restrict__ Cc,
  float* __restrict__ out)
{
  const int b = blockIdx.x, tid = threadIdx.x;
  __shared__ float qs[DK];
  __shared__ float sc[NH][SEQ];
  __shared__ float at[NH][SEQ];
  __shared__ float red[4];
  for (int i=tid; i<DK; i+=256) qs[i] = q[(size_t)b*DK + i];
  __syncthreads();
  {
    const int p = tid>>2, sub = tid&3, h = p>>4, s = p&15;
    const unsigned short* krow = Km + ((size_t)b*SEQ + s)*DK + h*DH + sub*32;
    const float* qh = &qs[h*DH + sub*32];
    float part = 0.f;
    #pragma unroll
    for (int c8=0;c8<4;++c8){
      u16x8 kv = *(const u16x8*)(krow + c8*8);
      #pragma unroll
      for (int j=0;j<8;++j) part += qh[c8*8+j]*bf2f(kv[j]);
    }
    part += __shfl_xor(part,1); part += __shfl_xor(part,2);
    if (sub==0) sc[h][s] = part * 0.08838834764831845f;  // 1/sqrt(128)
  }
  __syncthreads();
  if (tid < 64){
    const int h = tid>>4;
    float v = sc[h][tid&15], mx = v;
    #pragma unroll
    for (int m=1;m<16;m<<=1) mx = fmaxf(mx, __shfl_xor(mx,m));
    float e = __expf(v-mx), se = e;
    #pragma unroll
    for (int m=1;m<16;m<<=1) se += __shfl_xor(se,m);
    at[h][tid&15] = e/se;
  }
  __syncthreads();
  float accum = 0.f;
  #pragma unroll
  for (int it=0; it<4; ++it){
    const int idx = it*256 + tid;
    const int h = idx>>8, d0 = (idx&255)*2;
    const unsigned short* lo = lo_all + (size_t)b*SEQ*HID + d0;
    float p0=0.f, p1=0.f;
    #pragma unroll
    for (int s=0;s<16;++s){
      unsigned int pr = *(const unsigned int*)(lo + s*HID);
      float a = at[h][s];
      p0 += a*bf2f((unsigned short)(pr&0xffffu));
      p1 += a*bf2f((unsigned short)(pr>>16));
    }
    accum += u[h*HID+d0]*p0 + u[h*HID+d0+1]*p1;
  }
  #pragma unroll
  for (int m=32;m;m>>=1) accum += __shfl_xor(accum,m);
  if ((tid&63)==0) red[tid>>6] = accum;
  __syncthreads();
  if (tid==0) out[1+b] = red[0]+red[1]+red[2]+red[3] + Cc[0];
}

__global__ __launch_bounds__(256) void loss_k(const float* __restrict__ label, float* __restrict__ out){
  const int tid = threadIdx.x;
  __shared__ float red[4];
  float s = 0.f;
  for (int b=tid; b<B_SZ; b+=256){
    float d = out[1+b] - label[(size_t)b*SEQ + (SEQ-1)];
    s += d*d;
  }
  #pragma unroll
  for (int m=32;m;m>>=1) s += __shfl_xor(s,m);
  if ((tid&63)==0) red[tid>>6]=s;
  __syncthreads();
  if (tid==0) out[0] = (red[0]+red[1]+red[2]+red[3]) * (1.f/B_SZ);
}

__global__ __launch_bounds__(256) void cvt_bf16_k(const float* __restrict__ in, unsigned short* __restrict__ o, int n){
  int i = (blockIdx.x*256 + threadIdx.x)*4;
  if (i < n){
    f4_t v = *(const f4_t*)&in[i];
    u16x4 w;
    #pragma unroll
    for (int j=0;j<4;++j) w[j] = f2bf(v[j]);
    *(u16x4*)&o[i] = w;
  }
}

// concat+convert the 4 modality tensors into modsB[32768][4096] bf16
__global__ __launch_bounds__(256) void cvt4_k(
  const float* __restrict__ v0, const float* __restrict__ v1,
  const float* __restrict__ v2, const float* __restrict__ v3,
  unsigned short* __restrict__ dst)
{
  const int idx = blockIdx.x*256 + threadIdx.x;   // 8 elements each
  const int src = blockIdx.y;
  const float* s = src==0?v0 : src==1?v1 : src==2?v2 : v3;
  const size_t e0 = (size_t)idx*8;
  const int row = (int)(e0 >> 10);
  const int col = (int)(e0 & 1023);
  f4_t a = *(const f4_t*)&s[e0];
  f4_t b = *(const f4_t*)&s[e0+4];
  u16x8 w;
  #pragma unroll
  for (int j=0;j<4;++j){ w[j]=f2bf(a[j]); w[4+j]=f2bf(b[j]); }
  *(u16x8*)&dst[(size_t)row*4096 + src*1024 + col] = w;
}

// -------- fold wout/out_W/wv into u[h,d] and scalar C (exact: sum(attn)==1) --------
__global__ __launch_bounds__(256) void fold_we_k(
  const float* __restrict__ wout_W, const float* __restrict__ out_W, float* __restrict__ we)
{
  const int j = blockIdx.x*256 + threadIdx.x;   // 2048
  float s=0.f;
  for (int m=0;m<512;++m) s += out_W[m]*wout_W[(size_t)m*2048+j];
  we[j]=s;
}
__global__ __launch_bounds__(256) void fold_u_k(
  const float* __restrict__ we, const float* __restrict__ wv_W, float* __restrict__ u)
{
  const int o = blockIdx.x*256 + threadIdx.x;   // 2048
  const int h = o>>9, d = o&511;
  const float* wv = wv_W + (size_t)h*262144 + d;
  const float* wp = we + h*512;
  float s=0.f;
  for (int k=0;k<512;++k) s += wp[k]*wv[(size_t)k*512];
  u[o]=s;
}
__global__ __launch_bounds__(256) void fold_c_k(
  const float* __restrict__ we, const float* __restrict__ wv_b,
  const float* __restrict__ out_W, const float* __restrict__ wout_b,
  const float* __restrict__ out_b, float* __restrict__ Cc)
{
  const int tid = threadIdx.x;
  __shared__ float red[4];
  float s=0.f;
  for (int j=tid;j<2048;j+=256) s += we[j]*wv_b[j];
  for (int m=tid;m<512;m+=256)  s += out_W[m]*wout_b[m];
  #pragma unroll
  for (int m=32;m;m>>=1) s += __shfl_xor(s,m);
  if ((tid&63)==0) red[tid>>6]=s;
  __syncthreads();
  if (tid==0) Cc[0] = red[0]+red[1]+red[2]+red[3] + out_b[0];
}

extern "C" void kernel_launch(void* const* d_in, const int* in_sizes, int n_in,
                              void* d_out, int out_size, void* d_ws, size_t ws_size,
                              hipStream_t stream)
{
  const float* visual = (const float*)d_in[0];
  const float* text   = (const float*)d_in[1];
  const float* user_  = (const float*)d_in[2];
  const float* cat_   = (const float*)d_in[3];
  const float* label  = (const float*)d_in[4];
  const float* h0     = (const float*)d_in[5];
  const float* c0     = (const float*)d_in[6];
  const float* fus_W  = (const float*)d_in[7];
  const float* fus_b  = (const float*)d_in[8];
  const float* W_ih   = (const float*)d_in[9];
  const float* W_hh   = (const float*)d_in[10];
  const float* g_ih   = (const float*)d_in[11];
  const float* b_ih   = (const float*)d_in[12];
  const float* g_hh   = (const float*)d_in[13];
  const float* b_hh   = (const float*)d_in[14];
  const float* g_c    = (const float*)d_in[15];
  const float* b_c    = (const float*)d_in[16];
  const float* wq_W   = (const float*)d_in[17];
  const float* wq_b   = (const float*)d_in[18];
  const float* wk_W   = (const float*)d_in[19];
  const float* wk_b   = (const float*)d_in[20];
  const float* wv_W   = (const float*)d_in[21];
  const float* wv_b   = (const float*)d_in[22];
  const float* wout_W = (const float*)d_in[23];
  const float* wout_b = (const float*)d_in[24];
  const float* out_W  = (const float*)d_in[25];
  const float* out_b  = (const float*)d_in[26];
  (void)in_sizes; (void)n_in; (void)out_size; (void)ws_size;

  char* base = (char*)d_ws; size_t off = 0;
  auto alloc = [&](size_t n)->void*{ void* p = base+off; off += n; off = (off+255)&~(size_t)255; return p; };
  unsigned short* modsB = (unsigned short*)alloc((size_t)32768*4096*2);  // 256 MB; reused as X
  unsigned short* X     = modsB;                                         // 128 MB alias (modsB dead after GEMM1)
  unsigned short* vt    = (unsigned short*)alloc((size_t)32768*1024*2);
  unsigned short* Gh    = (unsigned short*)alloc((size_t)2048*2048*2);
  float*          cws   = (float*)         alloc((size_t)2048*512*4);
  unsigned short* hb    = (unsigned short*)alloc((size_t)2048*512*2);
  unsigned short* lo    = (unsigned short*)alloc((size_t)32768*512*2);
  unsigned short* Km    = (unsigned short*)alloc((size_t)32768*512*2);
  float*          qb    = (float*)         alloc((size_t)2048*512*4);
  unsigned short* fusWb = (unsigned short*)alloc((size_t)1024*4096*2);
  unsigned short* Wihb  = (unsigned short*)alloc((size_t)2048*1024*2);
  unsigned short* Whhb  = (unsigned short*)alloc((size_t)2048*512*2);
  unsigned short* wqb   = (unsigned short*)alloc((size_t)512*512*2);
  unsigned short* wkb   = (unsigned short*)alloc((size_t)512*512*2);
  float*          we_ws = (float*)         alloc(2048*4);
  float*          u_ws  = (float*)         alloc(2048*4);
  float*          C_ws  = (float*)         alloc(256);

  // conversions + folds
  cvt4_k<<<dim3(16384,4), dim3(256), 0, stream>>>(visual, text, user_, cat_, modsB);
  cvt_bf16_k<<<dim3(4096), dim3(256), 0, stream>>>(fus_W, fusWb, 1024*4096);
  cvt_bf16_k<<<dim3(2048), dim3(256), 0, stream>>>(W_ih,  Wihb,  2048*1024);
  cvt_bf16_k<<<dim3(1024), dim3(256), 0, stream>>>(W_hh,  Whhb,  2048*512);
  cvt_bf16_k<<<dim3(256),  dim3(256), 0, stream>>>(wq_W,  wqb,   512*512);
  cvt_bf16_k<<<dim3(256),  dim3(256), 0, stream>>>(wk_W,  wkb,   512*512);
  cvt_bf16_k<<<dim3(1024), dim3(256), 0, stream>>>(h0,    hb,    2048*512);
  fold_we_k<<<dim3(8), dim3(256), 0, stream>>>(wout_W, out_W, we_ws);
  fold_u_k <<<dim3(8), dim3(256), 0, stream>>>(we_ws, wv_W, u_ws);
  fold_c_k <<<dim3(1), dim3(256), 0, stream>>>(we_ws, wv_b, out_W, wout_b, out_b, C_ws);

  // GEMM1: vt = relu(modsB @ fus_W^T + fus_b)   M=32768 N=1024 K=4096
  gemm16<true,true,true><<<dim3(2048), dim3(256), 0, stream>>>(
      modsB, fusWb, fus_b, vt, 1024, 4096, 2048);
  // GEMM2: X = vt @ W_ih^T  (bf16 out; LN renormalizes)  M=32768 N=2048 K=1024
  gemm16<true,false,false><<<dim3(4096), dim3(256), 0, stream>>>(
      vt, Wihb, nullptr, X, 2048, 1024, 4096);

  // recurrence
  for (int t=0; t<SEQ; ++t){
    gemm16<true,false,false><<<dim3(256), dim3(256), 0, stream>>>(
        hb, Whhb, nullptr, Gh, 2048, 512, 256);
    lstm_step<<<dim3(2048), dim3(256), 0, stream>>>(
        X, Gh, (t==0 ? c0 : cws), cws, g_ih, b_ih, g_hh, b_hh, g_c, b_c, hb, lo, t);
  }

  // q = hn @ wq_W^T + wq_b   (fp32 out)  M=2048 N=512 K=512
  gemm16<false,true,false><<<dim3(64), dim3(256), 0, stream>>>(
      hb, wqb, wq_b, qb, 512, 512, 64);
  // Kmat = lstm_out @ wk_W^T + wk_b  (bf16 out)  M=32768 N=512 K=512
  gemm16<true,true,false><<<dim3(1024), dim3(256), 0, stream>>>(
      lo, wkb, wk_b, Km, 512, 512, 1024);

  attn_out_k<<<dim3(2048), dim3(256), 0, stream>>>(qb, Km, lo, u_ws, C_ws, (float*)d_out);
  loss_k<<<dim3(1), dim3(256), 0, stream>>>(label, (float*)d_out);
}

// Round 3
// 1038.650 us; speedup vs baseline: 1.5450x; 1.1430x over previous
//
#include <hip/hip_runtime.h>
#include <cstdint>

#define B_SZ 2048
#define SEQ  16
#define DIM  1024
#define HID  512
#define DK   512
#define NH   4
#define DH   128
#define GATE 2048
#define EPSV 1e-5f

typedef __bf16 bf8_t __attribute__((ext_vector_type(8)));
typedef float  f4_t  __attribute__((ext_vector_type(4)));
typedef unsigned short u16x8 __attribute__((ext_vector_type(8)));
typedef unsigned short u16x4 __attribute__((ext_vector_type(4)));

__device__ __forceinline__ unsigned short f2bf(float f){
  __bf16 h = (__bf16)f;                       // RNE
  return __builtin_bit_cast(unsigned short, h);
}
__device__ __forceinline__ float bf2f(unsigned short u){
  return __builtin_bit_cast(float, ((unsigned int)u) << 16);
}
__device__ __forceinline__ float sigm(float x){ return 1.f/(1.f+__expf(-x)); }
__device__ __forceinline__ float tanh_f(float x){ return 1.f - 2.f/(__expf(2.f*x)+1.f); }

__device__ __forceinline__ void gload16(const void* g, void* l){
  __builtin_amdgcn_global_load_lds(
      (const __attribute__((address_space(1))) void*)g,
      (__attribute__((address_space(3))) void*)l, 16, 0, 0);
}

// ------------- bf16 BT GEMM 128x128 (m97 structure + granule-XOR swizzle) -------------
// C = A(MxK) @ B(NxK)^T. Rule-21: linear LDS dest, inverse-swizzled global SOURCE
// (granule ^= row&7 within each 128B row), same XOR on ds_read address.
template<bool OUT_BF16, bool BIAS, bool RELU>
__global__ __launch_bounds__(256) void gemm16(
    const unsigned short* __restrict__ A,
    const unsigned short* __restrict__ Bw,
    const float* __restrict__ bias,
    void* __restrict__ Cp,
    int N, int K, int nwg)
{
  __shared__ __align__(16) unsigned short As[128*64];
  __shared__ __align__(16) unsigned short Bs[128*64];
  const int tid = threadIdx.x, lane = tid & 63, wave = tid >> 6;
  const int bid = blockIdx.x;
  const int swz = (bid & 7)*(nwg >> 3) + (bid >> 3);   // nwg % 8 == 0 at all call sites
  const int nx  = N >> 7;
  const int lnx = 31 - __clz(nx);
  const int bm0 = (swz >> lnx) << 7;
  const int bn0 = (swz & (nx-1)) << 7;

  const int r8  = lane >> 3;                 // row within 8-row chunk (= row&7)
  const int gsw = ((lane & 7) ^ r8) * 8;     // swizzled source granule (shorts)
  const unsigned short* Ab = A  + (size_t)(bm0 + wave*32 + r8)*K + gsw;
  const unsigned short* Bb = Bw + (size_t)(bn0 + wave*32 + r8)*K + gsw;
  unsigned short* la = As + wave*2048;       // wave-uniform LDS base
  unsigned short* lb = Bs + wave*2048;

  f4_t acc[4][4];
  #pragma unroll
  for (int m=0;m<4;++m)
    #pragma unroll
    for (int n=0;n<4;++n) acc[m][n] = (f4_t)0.f;

  const int KT = K >> 6;
  const int fr = lane & 15, kg = lane >> 4;
  const int wm = (wave & 1)*64, wn = (wave >> 1)*64;

  for (int kt = 0; kt < KT; ++kt){
    if (kt) __syncthreads();                       // all waves done reading LDS
    const size_t ko = (size_t)kt*64;
    #pragma unroll
    for (int q = 0; q < 4; ++q){
      gload16(Ab + ko + (size_t)q*8*K, la + q*512);
      gload16(Bb + ko + (size_t)q*8*K, lb + q*512);
    }
    __syncthreads();                               // vmcnt(0) drained -> tiles ready
    #pragma unroll
    for (int kk = 0; kk < 2; ++kk){
      bf8_t af[4], bf_[4];
      #pragma unroll
      for (int m=0;m<4;++m){
        const int r = wm+m*16+fr;
        af[m]  = *(const bf8_t*)&As[r*64 + (((kk*4+kg) ^ (r&7))*8)];
      }
      #pragma unroll
      for (int n=0;n<4;++n){
        const int r = wn+n*16+fr;
        bf_[n] = *(const bf8_t*)&Bs[r*64 + (((kk*4+kg) ^ (r&7))*8)];
      }
      #pragma unroll
      for (int m=0;m<4;++m)
        #pragma unroll
        for (int n=0;n<4;++n)
          acc[m][n] = __builtin_amdgcn_mfma_f32_16x16x32_bf16(af[m], bf_[n], acc[m][n], 0,0,0);
    }
  }

  #pragma unroll
  for (int n=0;n<4;++n){
    const int col = bn0 + wn + n*16 + fr;
    float bv = 0.f;
    if constexpr (BIAS) bv = bias[col];
    #pragma unroll
    for (int m=0;m<4;++m){
      #pragma unroll
      for (int j=0;j<4;++j){
        const int row = bm0 + wm + m*16 + kg*4 + j;
        float v = acc[m][n][j] + bv;
        if constexpr (RELU) v = fmaxf(v, 0.f);
        if constexpr (OUT_BF16) ((unsigned short*)Cp)[(size_t)row*N + col] = f2bf(v);
        else                    ((float*)Cp)[(size_t)row*N + col] = v;
      }
    }
  }
}

// ------------- bf16 BT GEMM 64x64 (high-occupancy, for the small recurrent GEMMs) -------------
template<bool OUT_BF16, bool BIAS>
__global__ __launch_bounds__(256) void gemm64(
    const unsigned short* __restrict__ A,
    const unsigned short* __restrict__ Bw,
    const float* __restrict__ bias,
    void* __restrict__ Cp,
    int N, int K, int nwg)
{
  __shared__ __align__(16) unsigned short As[64*64];
  __shared__ __align__(16) unsigned short Bs[64*64];
  const int tid = threadIdx.x, lane = tid & 63, wave = tid >> 6;
  const int bid = blockIdx.x;
  const int swz = (bid & 7)*(nwg >> 3) + (bid >> 3);
  const int nx  = N >> 6;
  const int lnx = 31 - __clz(nx);
  const int bm0 = (swz >> lnx) << 6;
  const int bn0 = (swz & (nx-1)) << 6;

  const int r8  = lane >> 3;
  const int gsw = ((lane & 7) ^ r8) * 8;
  const unsigned short* Ab = A  + (size_t)(bm0 + wave*16 + r8)*K + gsw;
  const unsigned short* Bb = Bw + (size_t)(bn0 + wave*16 + r8)*K + gsw;
  unsigned short* la = As + wave*1024;
  unsigned short* lb = Bs + wave*1024;

  f4_t acc[2][2];
  #pragma unroll
  for (int m=0;m<2;++m)
    #pragma unroll
    for (int n=0;n<2;++n) acc[m][n] = (f4_t)0.f;

  const int KT = K >> 6;
  const int fr = lane & 15, kg = lane >> 4;
  const int wm = (wave & 1)*32, wn = (wave >> 1)*32;

  for (int kt = 0; kt < KT; ++kt){
    if (kt) __syncthreads();
    const size_t ko = (size_t)kt*64;
    #pragma unroll
    for (int q = 0; q < 2; ++q){
      gload16(Ab + ko + (size_t)q*8*K, la + q*512);
      gload16(Bb + ko + (size_t)q*8*K, lb + q*512);
    }
    __syncthreads();
    #pragma unroll
    for (int kk = 0; kk < 2; ++kk){
      bf8_t af[2], bf_[2];
      #pragma unroll
      for (int m=0;m<2;++m){
        const int r = wm+m*16+fr;
        af[m]  = *(const bf8_t*)&As[r*64 + (((kk*4+kg) ^ (r&7))*8)];
      }
      #pragma unroll
      for (int n=0;n<2;++n){
        const int r = wn+n*16+fr;
        bf_[n] = *(const bf8_t*)&Bs[r*64 + (((kk*4+kg) ^ (r&7))*8)];
      }
      #pragma unroll
      for (int m=0;m<2;++m)
        #pragma unroll
        for (int n=0;n<2;++n)
          acc[m][n] = __builtin_amdgcn_mfma_f32_16x16x32_bf16(af[m], bf_[n], acc[m][n], 0,0,0);
    }
  }

  #pragma unroll
  for (int n=0;n<2;++n){
    const int col = bn0 + wn + n*16 + fr;
    float bv = 0.f;
    if constexpr (BIAS) bv = bias[col];
    #pragma unroll
    for (int m=0;m<2;++m){
      #pragma unroll
      for (int j=0;j<4;++j){
        const int row = bm0 + wm + m*16 + kg*4 + j;
        float v = acc[m][n][j] + bv;
        if constexpr (OUT_BF16) ((unsigned short*)Cp)[(size_t)row*N + col] = f2bf(v);
        else                    ((float*)Cp)[(size_t)row*N + col] = v;
      }
    }
  }
}

// ---------------- fused LN + LSTM elementwise step (one WG per batch row) ----------------
__global__ __launch_bounds__(256) void lstm_step(
  const unsigned short* __restrict__ X, const unsigned short* __restrict__ Gh,
  const float* __restrict__ c_src, float* __restrict__ c_dst,
  const float* __restrict__ g_ih, const float* __restrict__ b_ih,
  const float* __restrict__ g_hh, const float* __restrict__ b_hh,
  const float* __restrict__ g_c,  const float* __restrict__ b_c,
  unsigned short* __restrict__ h_out, unsigned short* __restrict__ lstm_out,
  int t)
{
  const int b = blockIdx.x, tid = threadIdx.x;
  __shared__ float xs[GATE];
  __shared__ float gs[GATE];
  __shared__ float red[32];
  const unsigned short* xrow = X  + ((size_t)b*SEQ + t)*GATE;
  const unsigned short* grow = Gh + (size_t)b*GATE;
  u16x8 xv = *(const u16x8*)&xrow[tid*8];
  u16x8 gv = *(const u16x8*)&grow[tid*8];
  float sx=0,sx2=0,sg=0,sg2=0;
  #pragma unroll
  for (int j=0;j<8;++j){
    float x = bf2f(xv[j]), g = bf2f(gv[j]);
    xs[tid*8+j]=x; gs[tid*8+j]=g;
    sx += x; sx2 += x*x; sg += g; sg2 += g*g;
  }
  #pragma unroll
  for (int m=32;m;m>>=1){
    sx += __shfl_xor(sx,m); sx2 += __shfl_xor(sx2,m);
    sg += __shfl_xor(sg,m); sg2 += __shfl_xor(sg2,m);
  }
  const int w = tid>>6;
  if ((tid&63)==0){ red[w]=sx; red[4+w]=sx2; red[8+w]=sg; red[12+w]=sg2; }
  __syncthreads();
  sx  = red[0]+red[1]+red[2]+red[3];
  sx2 = red[4]+red[5]+red[6]+red[7];
  sg  = red[8]+red[9]+red[10]+red[11];
  sg2 = red[12]+red[13]+red[14]+red[15];
  const float mX = sx*(1.f/GATE), mH = sg*(1.f/GATE);
  const float rX = rsqrtf(sx2*(1.f/GATE)-mX*mX+EPSV);
  const float rH = rsqrtf(sg2*(1.f/GATE)-mH*mH+EPSV);

  float cN[2], xo[2]; float sc=0, sc2=0;
  #pragma unroll
  for (int rep=0;rep<2;++rep){
    const int n = tid + rep*256;
    const int ni=n, nf=n+HID, ng=n+2*HID, no=n+3*HID;
    float gi = (xs[ni]-mX)*rX*g_ih[ni]+b_ih[ni] + (gs[ni]-mH)*rH*g_hh[ni]+b_hh[ni];
    float gf = (xs[nf]-mX)*rX*g_ih[nf]+b_ih[nf] + (gs[nf]-mH)*rH*g_hh[nf]+b_hh[nf];
    float gg = (xs[ng]-mX)*rX*g_ih[ng]+b_ih[ng] + (gs[ng]-mH)*rH*g_hh[ng]+b_hh[ng];
    float go = (xs[no]-mX)*rX*g_ih[no]+b_ih[no] + (gs[no]-mH)*rH*g_hh[no]+b_hh[no];
    float co = c_src[(size_t)b*HID + n];
    float cn = sigm(gf)*co + sigm(gi)*tanh_f(gg);
    cN[rep]=cn; xo[rep]=go;
    sc += cn; sc2 += cn*cn;
  }
  #pragma unroll
  for (int m=32;m;m>>=1){ sc += __shfl_xor(sc,m); sc2 += __shfl_xor(sc2,m); }
  if ((tid&63)==0){ red[16+w]=sc; red[20+w]=sc2; }
  __syncthreads();
  sc  = red[16]+red[17]+red[18]+red[19];
  sc2 = red[20]+red[21]+red[22]+red[23];
  const float mC = sc*(1.f/HID);
  const float rC = rsqrtf(sc2*(1.f/HID)-mC*mC+EPSV);
  #pragma unroll
  for (int rep=0;rep<2;++rep){
    const int n = tid + rep*256;
    float hN = sigm(xo[rep])*tanh_f((cN[rep]-mC)*rC*g_c[n]+b_c[n]);
    c_dst[(size_t)b*HID+n] = cN[rep];
    unsigned short hbv = f2bf(hN);
    h_out[(size_t)b*HID+n] = hbv;
    lstm_out[((size_t)b*SEQ+t)*HID+n] = hbv;
  }
}

// ---------------- fused attention: scores -> softmax -> pooled -> scalar out ----------------
__global__ __launch_bounds__(256) void attn_out_k(
  const float* __restrict__ q, const unsigned short* __restrict__ Km,
  const unsigned short* __restrict__ lo_all,
  const float* __restrict__ u, const float* __restrict__ Cc,
  float* __restrict__ out)
{
  const int b = blockIdx.x, tid = threadIdx.x;
  __shared__ float qs[DK];
  __shared__ float sc[NH][SEQ];
  __shared__ float at[NH][SEQ];
  __shared__ float red[4];
  for (int i=tid; i<DK; i+=256) qs[i] = q[(size_t)b*DK + i];
  __syncthreads();
  {
    const int p = tid>>2, sub = tid&3, h = p>>4, s = p&15;
    const unsigned short* krow = Km + ((size_t)b*SEQ + s)*DK + h*DH + sub*32;
    const float* qh = &qs[h*DH + sub*32];
    float part = 0.f;
    #pragma unroll
    for (int c8=0;c8<4;++c8){
      u16x8 kv = *(const u16x8*)(krow + c8*8);
      #pragma unroll
      for (int j=0;j<8;++j) part += qh[c8*8+j]*bf2f(kv[j]);
    }
    part += __shfl_xor(part,1); part += __shfl_xor(part,2);
    if (sub==0) sc[h][s] = part * 0.08838834764831845f;  // 1/sqrt(128)
  }
  __syncthreads();
  if (tid < 64){
    const int h = tid>>4;
    float v = sc[h][tid&15], mx = v;
    #pragma unroll
    for (int m=1;m<16;m<<=1) mx = fmaxf(mx, __shfl_xor(mx,m));
    float e = __expf(v-mx), se = e;
    #pragma unroll
    for (int m=1;m<16;m<<=1) se += __shfl_xor(se,m);
    at[h][tid&15] = e/se;
  }
  __syncthreads();
  float accum = 0.f;
  #pragma unroll
  for (int it=0; it<4; ++it){
    const int idx = it*256 + tid;
    const int h = idx>>8, d0 = (idx&255)*2;
    const unsigned short* lo = lo_all + (size_t)b*SEQ*HID + d0;
    float p0=0.f, p1=0.f;
    #pragma unroll
    for (int s=0;s<16;++s){
      unsigned int pr = *(const unsigned int*)(lo + s*HID);
      float a = at[h][s];
      p0 += a*bf2f((unsigned short)(pr&0xffffu));
      p1 += a*bf2f((unsigned short)(pr>>16));
    }
    accum += u[h*HID+d0]*p0 + u[h*HID+d0+1]*p1;
  }
  #pragma unroll
  for (int m=32;m;m>>=1) accum += __shfl_xor(accum,m);
  if ((tid&63)==0) red[tid>>6] = accum;
  __syncthreads();
  if (tid==0) out[1+b] = red[0]+red[1]+red[2]+red[3] + Cc[0];
}

__global__ __launch_bounds__(256) void loss_k(const float* __restrict__ label, float* __restrict__ out){
  const int tid = threadIdx.x;
  __shared__ float red[4];
  float s = 0.f;
  for (int b=tid; b<B_SZ; b+=256){
    float d = out[1+b] - label[(size_t)b*SEQ + (SEQ-1)];
    s += d*d;
  }
  #pragma unroll
  for (int m=32;m;m>>=1) s += __shfl_xor(s,m);
  if ((tid&63)==0) red[tid>>6]=s;
  __syncthreads();
  if (tid==0) out[0] = (red[0]+red[1]+red[2]+red[3]) * (1.f/B_SZ);
}

__global__ __launch_bounds__(256) void cvt_bf16_k(const float* __restrict__ in, unsigned short* __restrict__ o, int n){
  int i = (blockIdx.x*256 + threadIdx.x)*4;
  if (i < n){
    f4_t v = *(const f4_t*)&in[i];
    u16x4 w;
    #pragma unroll
    for (int j=0;j<4;++j) w[j] = f2bf(v[j]);
    *(u16x4*)&o[i] = w;
  }
}

// concat+convert the 4 modality tensors into modsB[32768][4096] bf16
__global__ __launch_bounds__(256) void cvt4_k(
  const float* __restrict__ v0, const float* __restrict__ v1,
  const float* __restrict__ v2, const float* __restrict__ v3,
  unsigned short* __restrict__ dst)
{
  const int idx = blockIdx.x*256 + threadIdx.x;   // 8 elements each
  const int src = blockIdx.y;
  const float* s = src==0?v0 : src==1?v1 : src==2?v2 : v3;
  const size_t e0 = (size_t)idx*8;
  const int row = (int)(e0 >> 10);
  const int col = (int)(e0 & 1023);
  f4_t a = *(const f4_t*)&s[e0];
  f4_t b = *(const f4_t*)&s[e0+4];
  u16x8 w;
  #pragma unroll
  for (int j=0;j<4;++j){ w[j]=f2bf(a[j]); w[4+j]=f2bf(b[j]); }
  *(u16x8*)&dst[(size_t)row*4096 + src*1024 + col] = w;
}

// -------- fold wout/out_W/wv into u[h,d] and scalar C (exact: sum(attn)==1) --------
__global__ __launch_bounds__(256) void fold_we_k(
  const float* __restrict__ wout_W, const float* __restrict__ out_W, float* __restrict__ we)
{
  const int j = blockIdx.x*256 + threadIdx.x;   // 2048
  float s=0.f;
  for (int m=0;m<512;++m) s += out_W[m]*wout_W[(size_t)m*2048+j];
  we[j]=s;
}
__global__ __launch_bounds__(256) void fold_u_k(
  const float* __restrict__ we, const float* __restrict__ wv_W, float* __restrict__ u)
{
  const int o = blockIdx.x*256 + threadIdx.x;   // 2048
  const int h = o>>9, d = o&511;
  const float* wv = wv_W + (size_t)h*262144 + d;
  const float* wp = we + h*512;
  float s=0.f;
  for (int k=0;k<512;++k) s += wp[k]*wv[(size_t)k*512];
  u[o]=s;
}
__global__ __launch_bounds__(256) void fold_c_k(
  const float* __restrict__ we, const float* __restrict__ wv_b,
  const float* __restrict__ out_W, const float* __restrict__ wout_b,
  const float* __restrict__ out_b, float* __restrict__ Cc)
{
  const int tid = threadIdx.x;
  __shared__ float red[4];
  float s=0.f;
  for (int j=tid;j<2048;j+=256) s += we[j]*wv_b[j];
  for (int m=tid;m<512;m+=256)  s += out_W[m]*wout_b[m];
  #pragma unroll
  for (int m=32;m;m>>=1) s += __shfl_xor(s,m);
  if ((tid&63)==0) red[tid>>6]=s;
  __syncthreads();
  if (tid==0) Cc[0] = red[0]+red[1]+red[2]+red[3] + out_b[0];
}

extern "C" void kernel_launch(void* const* d_in, const int* in_sizes, int n_in,
                              void* d_out, int out_size, void* d_ws, size_t ws_size,
                              hipStream_t stream)
{
  const float* visual = (const float*)d_in[0];
  const float* text   = (const float*)d_in[1];
  const float* user_  = (const float*)d_in[2];
  const float* cat_   = (const float*)d_in[3];
  const float* label  = (const float*)d_in[4];
  const float* h0     = (const float*)d_in[5];
  const float* c0     = (const float*)d_in[6];
  const float* fus_W  = (const float*)d_in[7];
  const float* fus_b  = (const float*)d_in[8];
  const float* W_ih   = (const float*)d_in[9];
  const float* W_hh   = (const float*)d_in[10];
  const float* g_ih   = (const float*)d_in[11];
  const float* b_ih   = (const float*)d_in[12];
  const float* g_hh   = (const float*)d_in[13];
  const float* b_hh   = (const float*)d_in[14];
  const float* g_c    = (const float*)d_in[15];
  const float* b_c    = (const float*)d_in[16];
  const float* wq_W   = (const float*)d_in[17];
  const float* wq_b   = (const float*)d_in[18];
  const float* wk_W   = (const float*)d_in[19];
  const float* wk_b   = (const float*)d_in[20];
  const float* wv_W   = (const float*)d_in[21];
  const float* wv_b   = (const float*)d_in[22];
  const float* wout_W = (const float*)d_in[23];
  const float* wout_b = (const float*)d_in[24];
  const float* out_W  = (const float*)d_in[25];
  const float* out_b  = (const float*)d_in[26];
  (void)in_sizes; (void)n_in; (void)out_size; (void)ws_size;

  char* base = (char*)d_ws; size_t off = 0;
  auto alloc = [&](size_t n)->void*{ void* p = base+off; off += n; off = (off+255)&~(size_t)255; return p; };
  unsigned short* modsB = (unsigned short*)alloc((size_t)32768*4096*2);  // 256 MB; reused as X
  unsigned short* X     = modsB;                                         // 128 MB alias (modsB dead after GEMM1)
  unsigned short* vt    = (unsigned short*)alloc((size_t)32768*1024*2);
  unsigned short* Gh    = (unsigned short*)alloc((size_t)2048*2048*2);
  float*          cws   = (float*)         alloc((size_t)2048*512*4);
  unsigned short* hb    = (unsigned short*)alloc((size_t)2048*512*2);
  unsigned short* lo    = (unsigned short*)alloc((size_t)32768*512*2);
  unsigned short* Km    = (unsigned short*)alloc((size_t)32768*512*2);
  float*          qb    = (float*)         alloc((size_t)2048*512*4);
  unsigned short* fusWb = (unsigned short*)alloc((size_t)1024*4096*2);
  unsigned short* Wihb  = (unsigned short*)alloc((size_t)2048*1024*2);
  unsigned short* Whhb  = (unsigned short*)alloc((size_t)2048*512*2);
  unsigned short* wqb   = (unsigned short*)alloc((size_t)512*512*2);
  unsigned short* wkb   = (unsigned short*)alloc((size_t)512*512*2);
  float*          we_ws = (float*)         alloc(2048*4);
  float*          u_ws  = (float*)         alloc(2048*4);
  float*          C_ws  = (float*)         alloc(256);

  // conversions + folds
  cvt4_k<<<dim3(16384,4), dim3(256), 0, stream>>>(visual, text, user_, cat_, modsB);
  cvt_bf16_k<<<dim3(4096), dim3(256), 0, stream>>>(fus_W, fusWb, 1024*4096);
  cvt_bf16_k<<<dim3(2048), dim3(256), 0, stream>>>(W_ih,  Wihb,  2048*1024);
  cvt_bf16_k<<<dim3(1024), dim3(256), 0, stream>>>(W_hh,  Whhb,  2048*512);
  cvt_bf16_k<<<dim3(256),  dim3(256), 0, stream>>>(wq_W,  wqb,   512*512);
  cvt_bf16_k<<<dim3(256),  dim3(256), 0, stream>>>(wk_W,  wkb,   512*512);
  cvt_bf16_k<<<dim3(1024), dim3(256), 0, stream>>>(h0,    hb,    2048*512);
  fold_we_k<<<dim3(8), dim3(256), 0, stream>>>(wout_W, out_W, we_ws);
  fold_u_k <<<dim3(8), dim3(256), 0, stream>>>(we_ws, wv_W, u_ws);
  fold_c_k <<<dim3(1), dim3(256), 0, stream>>>(we_ws, wv_b, out_W, wout_b, out_b, C_ws);

  // GEMM1: vt = relu(modsB @ fus_W^T + fus_b)   M=32768 N=1024 K=4096
  gemm16<true,true,true><<<dim3(2048), dim3(256), 0, stream>>>(
      modsB, fusWb, fus_b, vt, 1024, 4096, 2048);
  // GEMM2: X = vt @ W_ih^T  (bf16 out; LN renormalizes)  M=32768 N=2048 K=1024
  gemm16<true,false,false><<<dim3(4096), dim3(256), 0, stream>>>(
      vt, Wihb, nullptr, X, 2048, 1024, 4096);

  // recurrence (64x64 tiles -> 1024 WGs, 4/CU)
  for (int t=0; t<SEQ; ++t){
    gemm64<true,false><<<dim3(1024), dim3(256), 0, stream>>>(
        hb, Whhb, nullptr, Gh, 2048, 512, 1024);
    lstm_step<<<dim3(2048), dim3(256), 0, stream>>>(
        X, Gh, (t==0 ? c0 : cws), cws, g_ih, b_ih, g_hh, b_hh, g_c, b_c, hb, lo, t);
  }

  // q = hn @ wq_W^T + wq_b   (fp32 out)  M=2048 N=512 K=512
  gemm64<false,true><<<dim3(256), dim3(256), 0, stream>>>(
      hb, wqb, wq_b, qb, 512, 512, 256);
  // Kmat = lstm_out @ wk_W^T + wk_b  (bf16 out)  M=32768 N=512 K=512
  gemm16<true,true,false><<<dim3(1024), dim3(256), 0, stream>>>(
      lo, wkb, wk_b, Km, 512, 512, 1024);

  attn_out_k<<<dim3(2048), dim3(256), 0, stream>>>(qb, Km, lo, u_ws, C_ws, (float*)d_out);
  loss_k<<<dim3(1), dim3(256), 0, stream>>>(label, (float*)d_out);
}